// Round 2
// baseline (2835.086 us; speedup 1.0000x reference)
//
#include <hip/hip_runtime.h>

// ContinuousFilterConvolution (SchNet CFConv), MI355X gfx950.
// V=50000, E=1600000, DH=128, NB=16. All fp32.
//
// out[v] = sum_{e: dest[e]==v} node_feats[src[e]] * relu(relu(rbf(d_e) @ W1) @ W2)

#define DHID 128
#define NBASE 16

constexpr int TE = 64;        // edges per tile
constexpr int THREADS = 512;  // 8 waves

__global__ void zero_out_kernel(float4* __restrict__ out, int n4) {
    int i = blockIdx.x * blockDim.x + threadIdx.x;
    if (i < n4) out[i] = make_float4(0.f, 0.f, 0.f, 0.f);
}

__global__ __launch_bounds__(THREADS, 2)
void cfconv_fused(const float* __restrict__ node_feats,
                  const float* __restrict__ coords,
                  const int* __restrict__ srcI,
                  const int* __restrict__ dstI,
                  const float* __restrict__ W1,
                  const float* __restrict__ W2,
                  float* __restrict__ out,
                  int E, int ntiles)
{
    __shared__ float sW2[DHID * DHID];   // [k][c] row-major, 64 KB
    __shared__ float sW1[NBASE * DHID];  // [b][k], 8 KB
    __shared__ float sM1[DHID * TE];     // m1 transposed: [k][e], 32 KB
    __shared__ int sSrc[TE];
    __shared__ int sDst[TE];

    const int tid = threadIdx.x;

    // Stage weights once per block (L2-hot after first block).
    for (int i = tid; i < DHID * DHID; i += THREADS) sW2[i] = W2[i];
    for (int i = tid; i < NBASE * DHID; i += THREADS) sW1[i] = W1[i];

    // GEMM-phase mapping: thread = (edge-group te 0..15) x (chan-group tc 0..31)
    const int tc = tid & 31;   // 4 channels: tc*4 .. tc*4+3
    const int te = tid >> 5;   // 4 edges:    te*4 .. te*4+3
    // m1-phase mapping: thread = (edge e_m1 0..63) x (k-group kg 0..7, 16 k each)
    const int e_m1 = tid & 63;
    const int kg = tid >> 6;

    constexpr float WIDTH = 4.5f / 15.0f;            // (D_MAX-D_MIN)/(NB-1)
    constexpr float COEFF = -0.5f / (WIDTH * WIDTH);

    for (int tile = blockIdx.x; tile < ntiles; tile += gridDim.x) {
        const int ebase = tile * TE;
        __syncthreads();  // protect sSrc/sDst/sM1 (and first-iter weight staging)
        if (tid < TE) {
            int e = ebase + tid;
            if (e >= E) e = E - 1;  // clamp (never triggers: E % TE == 0)
            sSrc[tid] = srcI[e];
        } else if (tid < 2 * TE) {
            int e = ebase + (tid - TE);
            if (e >= E) e = E - 1;
            sDst[tid - TE] = dstI[e];
        }
        __syncthreads();

        // ---- phase 1: sM1[k][e] = relu( rbf(d_e) @ W1 )[k]
        {
            const int s = sSrc[e_m1];
            const int dv = sDst[e_m1];
            const float dx = coords[s * 3 + 0] - coords[dv * 3 + 0];
            const float dy = coords[s * 3 + 1] - coords[dv * 3 + 1];
            const float dz = coords[s * 3 + 2] - coords[dv * 3 + 2];
            const float d = sqrtf(fmaf(dx, dx, fmaf(dy, dy, dz * dz)));
            float rbf[NBASE];
#pragma unroll
            for (int b = 0; b < NBASE; ++b) {
                const float t = d - WIDTH * (float)b;
                rbf[b] = __expf(COEFF * t * t);
            }
#pragma unroll
            for (int kk = 0; kk < 16; ++kk) {
                const int k = kg * 16 + kk;
                float acc = 0.f;
#pragma unroll
                for (int b = 0; b < NBASE; ++b)
                    acc = fmaf(rbf[b], sW1[b * DHID + k], acc);  // broadcast read
                sM1[k * TE + e_m1] = fmaxf(acc, 0.f);  // lane=e -> conflict-free
            }
        }
        __syncthreads();

        // ---- phase 2: register-tiled GEMM  m2[e][c] = sum_k m1[e][k]*W2[k][c]
        float acc[4][4];
#pragma unroll
        for (int i = 0; i < 4; ++i)
#pragma unroll
            for (int j = 0; j < 4; ++j) acc[i][j] = 0.f;

#pragma unroll 8
        for (int k = 0; k < DHID; ++k) {
            const float4 a4 = *(const float4*)&sM1[k * TE + te * 4];   // 2-addr broadcast
            const float4 b4 = *(const float4*)&sW2[k * DHID + tc * 4]; // 512B/wave stream
            const float av[4] = {a4.x, a4.y, a4.z, a4.w};
            const float bv[4] = {b4.x, b4.y, b4.z, b4.w};
#pragma unroll
            for (int i = 0; i < 4; ++i)
#pragma unroll
                for (int j = 0; j < 4; ++j)
                    acc[i][j] = fmaf(av[i], bv[j], acc[i][j]);
        }

        // ---- epilogue: relu, gather node_feats[src], scatter-add to out[dst]
#pragma unroll
        for (int i = 0; i < 4; ++i) {
            const int e = te * 4 + i;
            if (ebase + e < E) {
                const int s = sSrc[e];
                const int dv = sDst[e];
                const float4 nf = *(const float4*)&node_feats[s * DHID + tc * 4];
                float* op = &out[dv * DHID + tc * 4];
                atomicAdd(op + 0, fmaxf(acc[i][0], 0.f) * nf.x);
                atomicAdd(op + 1, fmaxf(acc[i][1], 0.f) * nf.y);
                atomicAdd(op + 2, fmaxf(acc[i][2], 0.f) * nf.z);
                atomicAdd(op + 3, fmaxf(acc[i][3], 0.f) * nf.w);
            }
        }
    }
}

extern "C" void kernel_launch(void* const* d_in, const int* in_sizes, int n_in,
                              void* d_out, int out_size, void* d_ws, size_t ws_size,
                              hipStream_t stream) {
    const float* node_feats = (const float*)d_in[0];
    const float* coords     = (const float*)d_in[1];
    const int*   srcI       = (const int*)d_in[2];
    const int*   dstI       = (const int*)d_in[3];
    const float* W1         = (const float*)d_in[4];
    const float* W2         = (const float*)d_in[5];
    float* out = (float*)d_out;

    const int E = in_sizes[2];

    // Zero-init output (harness poisons d_out with 0xAA before every launch).
    const int n4 = out_size / 4;  // out_size = 50000*128, divisible by 4
    zero_out_kernel<<<(n4 + 255) / 256, 256, 0, stream>>>((float4*)out, n4);

    const int ntiles = (E + TE - 1) / TE;
    int grid = ntiles < 2048 ? ntiles : 2048;
    cfconv_fused<<<grid, THREADS, 0, stream>>>(node_feats, coords, srcI, dstI,
                                               W1, W2, out, E, ntiles);
}

// Round 3
// 1519.179 us; speedup vs baseline: 1.8662x; 1.8662x over previous
//
#include <hip/hip_runtime.h>

// ContinuousFilterConvolution (SchNet CFConv), MI355X gfx950.
// V=50000, E=1600000, DH=128, NB=16. All fp32.
// Round 3: counting-sort edges by dest + segmented-reduction epilogue.
// Rationale: round-2 counters showed WRITE_SIZE=3.2GB (125x output size) from
// 204.8M random fp32 atomics -> HBM write-amplification bound (VALUBusy 22%).

#define DHID 128
#define NBASE 16

constexpr int TE = 64;        // edges per tile
constexpr int THREADS = 512;  // 8 waves

// ---------------- sort-by-dest machinery (rebuilt every launch) ----------------

__global__ void zero_kernel(float4* __restrict__ out4, int n4,
                            int* __restrict__ cursor, int V) {
    for (int i = blockIdx.x * blockDim.x + threadIdx.x; i < n4;
         i += gridDim.x * blockDim.x)
        out4[i] = make_float4(0.f, 0.f, 0.f, 0.f);
    for (int i = blockIdx.x * blockDim.x + threadIdx.x; i < V;
         i += gridDim.x * blockDim.x)
        cursor[i] = 0;
}

__global__ void hist_kernel(const int* __restrict__ dstI, int E,
                            int* __restrict__ cursor) {
    for (int i = blockIdx.x * blockDim.x + threadIdx.x; i < E;
         i += gridDim.x * blockDim.x)
        atomicAdd(&cursor[dstI[i]], 1);
}

// single-block exclusive scan of cursor[0..V) in place (counts -> bucket starts)
__global__ void scan_kernel(int* __restrict__ cursor, int V) {
    __shared__ int s[1024];
    __shared__ int s_carry;
    const int tid = threadIdx.x;
    if (tid == 0) s_carry = 0;
    __syncthreads();
    for (int base = 0; base < V; base += 1024) {
        const int i = base + tid;
        const int c = (i < V) ? cursor[i] : 0;
        s[tid] = c;
        __syncthreads();
        int run = c;
        for (int off = 1; off < 1024; off <<= 1) {
            const int add = (tid >= off) ? s[tid - off] : 0;
            __syncthreads();
            run += add;
            s[tid] = run;
            __syncthreads();
        }
        const int carry = s_carry;
        if (i < V) cursor[i] = carry + run - c;  // exclusive prefix
        __syncthreads();
        if (tid == 1023) s_carry = carry + run;  // add chunk total
        __syncthreads();
    }
}

__global__ void scatter_kernel(const int* __restrict__ dstI, int E,
                               int* __restrict__ cursor, int* __restrict__ perm) {
    for (int i = blockIdx.x * blockDim.x + threadIdx.x; i < E;
         i += gridDim.x * blockDim.x) {
        const int pos = atomicAdd(&cursor[dstI[i]], 1);
        perm[pos] = i;
    }
}

// ---------------- fused CFConv over dest-sorted edges ----------------

__global__ __launch_bounds__(THREADS, 2)
void cfconv_sorted(const float* __restrict__ node_feats,
                   const float* __restrict__ coords,
                   const int* __restrict__ srcI,
                   const int* __restrict__ dstI,
                   const float* __restrict__ W1,
                   const float* __restrict__ W2,
                   const int* __restrict__ perm,
                   float* __restrict__ out,
                   int E, int ntiles)
{
    __shared__ float sW2[DHID * DHID];   // [k][c], 64 KB
    __shared__ float sW1[NBASE * DHID];  // [b][k], 8 KB
    __shared__ float sM1[DHID * TE];     // phase1: [k][e]; epilogue reuse: sMsg[e][c] (32 KB)
    __shared__ int sSrc[TE];
    __shared__ int sDst[TE];

    const int tid = threadIdx.x;

    for (int i = tid; i < DHID * DHID; i += THREADS) sW2[i] = W2[i];
    for (int i = tid; i < NBASE * DHID; i += THREADS) sW1[i] = W1[i];

    const int tc = tid & 31;   // channel quad: tc*4 .. tc*4+3
    const int te = tid >> 5;   // edge group:   te*4 .. te*4+3
    const int e_m1 = tid & 63; // phase-1 edge
    const int kg = tid >> 6;   // phase-1 k-group (16 k each)

    constexpr float WIDTH = 4.5f / 15.0f;
    constexpr float COEFF = -0.5f / (WIDTH * WIDTH);

    for (int tile = blockIdx.x; tile < ntiles; tile += gridDim.x) {
        const int ebase = tile * TE;
        __syncthreads();  // (A) prev tile's flush done with sMsg/sDst
        if (tid < TE) {
            const int e = ebase + tid;
            const int pe = perm[e < E ? e : E - 1];
            sSrc[tid] = srcI[pe];
            sDst[tid] = dstI[pe];  // sorted ascending within and across tiles
        }
        __syncthreads();  // (B)

        // ---- phase 1: sM1[k][e] = relu( rbf(d_e) @ W1 )[k]
        {
            const int s = sSrc[e_m1];
            const int dv = sDst[e_m1];
            const float dx = coords[s * 3 + 0] - coords[dv * 3 + 0];
            const float dy = coords[s * 3 + 1] - coords[dv * 3 + 1];
            const float dz = coords[s * 3 + 2] - coords[dv * 3 + 2];
            const float d = sqrtf(fmaf(dx, dx, fmaf(dy, dy, dz * dz)));
            float rbf[NBASE];
#pragma unroll
            for (int b = 0; b < NBASE; ++b) {
                const float t = d - WIDTH * (float)b;
                rbf[b] = __expf(COEFF * t * t);
            }
#pragma unroll
            for (int kk = 0; kk < 16; ++kk) {
                const int k = kg * 16 + kk;
                float acc = 0.f;
#pragma unroll
                for (int b = 0; b < NBASE; ++b)
                    acc = fmaf(rbf[b], sW1[b * DHID + k], acc);  // wave-broadcast read
                sM1[k * TE + e_m1] = fmaxf(acc, 0.f);
            }
        }
        __syncthreads();  // (C)

        // ---- phase 2: register-tiled GEMM  m2[e][c] = sum_k m1[e][k]*W2[k][c]
        float acc[4][4];
#pragma unroll
        for (int i = 0; i < 4; ++i)
#pragma unroll
            for (int j = 0; j < 4; ++j) acc[i][j] = 0.f;

#pragma unroll 8
        for (int k = 0; k < DHID; ++k) {
            const float4 a4 = *(const float4*)&sM1[k * TE + te * 4];   // 32B unique/wave
            const float4 b4 = *(const float4*)&sW2[k * DHID + tc * 4]; // 512B unique/wave
            const float av[4] = {a4.x, a4.y, a4.z, a4.w};
            const float bv[4] = {b4.x, b4.y, b4.z, b4.w};
#pragma unroll
            for (int i = 0; i < 4; ++i)
#pragma unroll
                for (int j = 0; j < 4; ++j)
                    acc[i][j] = fmaf(av[i], bv[j], acc[i][j]);
        }
        __syncthreads();  // (D) all waves done reading sM1 as m1

        // ---- epilogue a: msg = relu(m2) * node_feats[src]  -> sMsg[e][c] (reuse sM1)
#pragma unroll
        for (int i = 0; i < 4; ++i) {
            const int e = te * 4 + i;
            float4 m = make_float4(0.f, 0.f, 0.f, 0.f);
            if (ebase + e < E) {
                const int s = sSrc[e];
                const float4 nf = *(const float4*)&node_feats[(size_t)s * DHID + tc * 4];
                m.x = fmaxf(acc[i][0], 0.f) * nf.x;
                m.y = fmaxf(acc[i][1], 0.f) * nf.y;
                m.z = fmaxf(acc[i][2], 0.f) * nf.z;
                m.w = fmaxf(acc[i][3], 0.f) * nf.w;
            }
            *(float4*)&sM1[e * DHID + tc * 4] = m;
        }
        __syncthreads();  // (E)

        // ---- epilogue b: segmented flush. dest sorted -> compress runs.
        // 128 threads: 32 channel-quads x 4 scanners of 16 edges each.
        if (tid < 128) {
            const int c4 = tid & 31;
            const int sc = tid >> 5;
            float4 racc = make_float4(0.f, 0.f, 0.f, 0.f);
            int prev = sDst[sc * 16];
#pragma unroll
            for (int j = 0; j < 16; ++j) {
                const int e = sc * 16 + j;
                const int dv = sDst[e];
                const float4 m = *(const float4*)&sM1[e * DHID + c4 * 4];
                if (dv != prev) {
                    float* op = &out[(size_t)prev * DHID + c4 * 4];
                    atomicAdd(op + 0, racc.x);
                    atomicAdd(op + 1, racc.y);
                    atomicAdd(op + 2, racc.z);
                    atomicAdd(op + 3, racc.w);
                    racc = make_float4(0.f, 0.f, 0.f, 0.f);
                    prev = dv;
                }
                racc.x += m.x; racc.y += m.y; racc.z += m.z; racc.w += m.w;
            }
            float* op = &out[(size_t)prev * DHID + c4 * 4];
            atomicAdd(op + 0, racc.x);
            atomicAdd(op + 1, racc.y);
            atomicAdd(op + 2, racc.z);
            atomicAdd(op + 3, racc.w);
        }
    }
}

extern "C" void kernel_launch(void* const* d_in, const int* in_sizes, int n_in,
                              void* d_out, int out_size, void* d_ws, size_t ws_size,
                              hipStream_t stream) {
    const float* node_feats = (const float*)d_in[0];
    const float* coords     = (const float*)d_in[1];
    const int*   srcI       = (const int*)d_in[2];
    const int*   dstI       = (const int*)d_in[3];
    const float* W1         = (const float*)d_in[4];
    const float* W2         = (const float*)d_in[5];
    float* out = (float*)d_out;

    const int E = in_sizes[2];
    const int V = in_sizes[0] / DHID;

    // workspace: cursor[V] ints, then perm[E] ints  (~6.6 MB)
    int* cursor = (int*)d_ws;
    int* perm   = cursor + V;

    const int n4 = out_size / 4;
    zero_kernel<<<1024, 256, 0, stream>>>((float4*)out, n4, cursor, V);
    hist_kernel<<<2048, 256, 0, stream>>>(dstI, E, cursor);
    scan_kernel<<<1, 1024, 0, stream>>>(cursor, V);
    scatter_kernel<<<2048, 256, 0, stream>>>(dstI, E, cursor, perm);

    const int ntiles = (E + TE - 1) / TE;
    const int grid = ntiles < 512 ? ntiles : 512;
    cfconv_sorted<<<grid, THREADS, 0, stream>>>(node_feats, coords, srcI, dstI,
                                                W1, W2, perm, out, E, ntiles);
}

// Round 5
// 1381.870 us; speedup vs baseline: 2.0516x; 1.0994x over previous
//
#include <hip/hip_runtime.h>

// ContinuousFilterConvolution (SchNet CFConv), MI355X gfx950.
// V=50000, E=1600000, DH=128, NB=16. All fp32.
// Round 5 = round 4 resubmitted (container infra failure, no kernel verdict).
// TE=128 / 1024 threads (16 waves -> 4 waves/SIMD, was 2).
// Rationale: round-3 counters: VALUBusy 51%, Occupancy 23.6% (1 blk/CU,
// 2 waves/SIMD) -> half the time is unhidden latency + barrier drain.
// LDS = sW2(64K)+sM1(64K) = 131072B exactly; W1 via wave-uniform s_loads;
// src/dst re-read through perm (L1-hot) instead of LDS staging.

#define DHID 128
#define NBASE 16

constexpr int TE = 128;        // edges per tile
constexpr int THREADS = 1024;  // 16 waves

// ---------------- sort-by-dest machinery (rebuilt every launch) ----------------

__global__ void zero_kernel(float4* __restrict__ out4, int n4,
                            int* __restrict__ cursor, int V) {
    for (int i = blockIdx.x * blockDim.x + threadIdx.x; i < n4;
         i += gridDim.x * blockDim.x)
        out4[i] = make_float4(0.f, 0.f, 0.f, 0.f);
    for (int i = blockIdx.x * blockDim.x + threadIdx.x; i < V;
         i += gridDim.x * blockDim.x)
        cursor[i] = 0;
}

__global__ void hist_kernel(const int* __restrict__ dstI, int E,
                            int* __restrict__ cursor) {
    for (int i = blockIdx.x * blockDim.x + threadIdx.x; i < E;
         i += gridDim.x * blockDim.x)
        atomicAdd(&cursor[dstI[i]], 1);
}

// single-block exclusive scan, wave-shuffle based (2 barriers per 1024-chunk)
__global__ __launch_bounds__(1024)
void scan_kernel(int* __restrict__ cursor, int V) {
    __shared__ int sTot[16];
    const int tid = threadIdx.x;
    const int lane = tid & 63;
    const int wid = tid >> 6;
    int carry = 0;
    for (int base = 0; base < V; base += 1024) {
        const int i = base + tid;
        const int orig = (i < V) ? cursor[i] : 0;
        int val = orig;
#pragma unroll
        for (int off = 1; off < 64; off <<= 1) {
            const int n = __shfl_up(val, off, 64);
            if (lane >= off) val += n;
        }
        if (lane == 63) sTot[wid] = val;
        __syncthreads();
        if (wid == 0 && lane < 16) {
            int t = sTot[lane];
#pragma unroll
            for (int off = 1; off < 16; off <<= 1) {
                const int n = __shfl_up(t, off, 16);
                if (lane >= off) t += n;
            }
            sTot[lane] = t;  // inclusive scan of wave totals
        }
        __syncthreads();
        const int waveoff = wid ? sTot[wid - 1] : 0;
        if (i < V) cursor[i] = carry + waveoff + val - orig;  // exclusive
        const int ctot = sTot[15];
        __syncthreads();  // all reads of sTot done before next chunk overwrites
        carry += ctot;
    }
}

__global__ void scatter_kernel(const int* __restrict__ dstI, int E,
                               int* __restrict__ cursor, int* __restrict__ perm) {
    for (int i = blockIdx.x * blockDim.x + threadIdx.x; i < E;
         i += gridDim.x * blockDim.x) {
        const int pos = atomicAdd(&cursor[dstI[i]], 1);
        perm[pos] = i;
    }
}

// ---------------- fused CFConv over dest-sorted edges ----------------

__global__ __launch_bounds__(THREADS, 4)
void cfconv_sorted(const float* __restrict__ node_feats,
                   const float* __restrict__ coords,
                   const int* __restrict__ srcI,
                   const int* __restrict__ dstI,
                   const float* __restrict__ W1,
                   const float* __restrict__ W2,
                   const int* __restrict__ perm,
                   float* __restrict__ out,
                   int E, int ntiles)
{
    __shared__ float sW2[DHID * DHID];  // [k][c], 64 KB
    __shared__ float sM1[DHID * TE];    // phase1/2: [k][e]; epilogue: sMsg[e][c]; 64 KB

    const int tid = threadIdx.x;

    for (int i = tid; i < DHID * DHID; i += THREADS) sW2[i] = W2[i];

    const int tc = tid & 31;    // GEMM: channel quad tc*4..+3
    const int te = tid >> 5;    // GEMM: edges te*4..+3  (0..31)
    const int e1 = tid & 127;   // phase-1 edge
    const int kg = tid >> 7;    // phase-1 k-group (16 k each, wave-uniform)

    constexpr float WIDTH = 4.5f / 15.0f;
    constexpr float COEFF = -0.5f / (WIDTH * WIDTH);

    for (int tile = blockIdx.x; tile < ntiles; tile += gridDim.x) {
        const int ebase = tile * TE;
        __syncthreads();  // (A) prev tile's flush done reading sMsg

        // ---- phase 1: sM1[k][e] = relu( rbf(d_e) @ W1 )[k]
        {
            int ge = ebase + e1;
            if (ge >= E) ge = E - 1;  // never triggers: E % TE == 0
            const int pe = perm[ge];
            const int s = srcI[pe];
            const int dv = dstI[pe];
            const float dx = coords[s * 3 + 0] - coords[dv * 3 + 0];
            const float dy = coords[s * 3 + 1] - coords[dv * 3 + 1];
            const float dz = coords[s * 3 + 2] - coords[dv * 3 + 2];
            const float d = sqrtf(fmaf(dx, dx, fmaf(dy, dy, dz * dz)));
            float rbf[NBASE];
#pragma unroll
            for (int b = 0; b < NBASE; ++b) {
                const float t = d - WIDTH * (float)b;
                rbf[b] = __expf(COEFF * t * t);
            }
#pragma unroll
            for (int kk = 0; kk < 16; ++kk) {
                // kg is wave-uniform -> force SGPR so W1 reads become s_loads
                const int k = __builtin_amdgcn_readfirstlane(kg * 16 + kk);
                float a = 0.f;
#pragma unroll
                for (int b = 0; b < NBASE; ++b)
                    a = fmaf(rbf[b], W1[b * DHID + k], a);
                sM1[k * TE + e1] = fmaxf(a, 0.f);  // lane=e -> conflict-free
            }
        }
        __syncthreads();  // (B)

        // ---- phase 2: register-tiled GEMM  m2[e][c] = sum_k m1[e][k]*W2[k][c]
        float acc[4][4];
#pragma unroll
        for (int i = 0; i < 4; ++i)
#pragma unroll
            for (int j = 0; j < 4; ++j) acc[i][j] = 0.f;

#pragma unroll 8
        for (int k = 0; k < DHID; ++k) {
            const float4 a4 = *(const float4*)&sM1[k * TE + te * 4];   // 2-addr bcast
            const float4 b4 = *(const float4*)&sW2[k * DHID + tc * 4]; // 512B/wave
            const float av[4] = {a4.x, a4.y, a4.z, a4.w};
            const float bv[4] = {b4.x, b4.y, b4.z, b4.w};
#pragma unroll
            for (int i = 0; i < 4; ++i)
#pragma unroll
                for (int j = 0; j < 4; ++j)
                    acc[i][j] = fmaf(av[i], bv[j], acc[i][j]);
        }
        __syncthreads();  // (C) all waves done reading sM1 as m1

        // ---- epilogue a: msg = relu(m2) * node_feats[src]  -> sMsg[e][c]
#pragma unroll
        for (int i = 0; i < 4; ++i) {
            const int e = te * 4 + i;
            const int ge = ebase + e;
            float4 m = make_float4(0.f, 0.f, 0.f, 0.f);
            if (ge < E) {
                const int s = srcI[perm[ge]];  // L1-hot (read in phase 1)
                const float4 nf = *(const float4*)&node_feats[(size_t)s * DHID + tc * 4];
                m.x = fmaxf(acc[i][0], 0.f) * nf.x;
                m.y = fmaxf(acc[i][1], 0.f) * nf.y;
                m.z = fmaxf(acc[i][2], 0.f) * nf.z;
                m.w = fmaxf(acc[i][3], 0.f) * nf.w;
            }
            *(float4*)&sM1[e * DHID + tc * 4] = m;
        }
        __syncthreads();  // (E)

        // ---- epilogue b: segmented flush (dest-sorted -> compress runs).
        // 256 threads: 32 channel-quads x 8 scanners of 16 edges each.
        if (tid < 256) {
            const int c4 = tid & 31;
            const int sc = tid >> 5;
            int dvs[16];
#pragma unroll
            for (int j = 0; j < 16; ++j) {   // prefetch dests (L1-hot)
                int ge = ebase + sc * 16 + j;
                if (ge >= E) ge = E - 1;
                dvs[j] = dstI[perm[ge]];
            }
            float4 racc = make_float4(0.f, 0.f, 0.f, 0.f);
            int prev = dvs[0];
#pragma unroll 4
            for (int j = 0; j < 16; ++j) {
                const int e = sc * 16 + j;
                const float4 m = *(const float4*)&sM1[e * DHID + c4 * 4];
                if (dvs[j] != prev) {
                    float* op = &out[(size_t)prev * DHID + c4 * 4];
                    atomicAdd(op + 0, racc.x);
                    atomicAdd(op + 1, racc.y);
                    atomicAdd(op + 2, racc.z);
                    atomicAdd(op + 3, racc.w);
                    racc = make_float4(0.f, 0.f, 0.f, 0.f);
                    prev = dvs[j];
                }
                racc.x += m.x; racc.y += m.y; racc.z += m.z; racc.w += m.w;
            }
            float* op = &out[(size_t)prev * DHID + c4 * 4];
            atomicAdd(op + 0, racc.x);
            atomicAdd(op + 1, racc.y);
            atomicAdd(op + 2, racc.z);
            atomicAdd(op + 3, racc.w);
        }
    }
}

extern "C" void kernel_launch(void* const* d_in, const int* in_sizes, int n_in,
                              void* d_out, int out_size, void* d_ws, size_t ws_size,
                              hipStream_t stream) {
    const float* node_feats = (const float*)d_in[0];
    const float* coords     = (const float*)d_in[1];
    const int*   srcI       = (const int*)d_in[2];
    const int*   dstI       = (const int*)d_in[3];
    const float* W1         = (const float*)d_in[4];
    const float* W2         = (const float*)d_in[5];
    float* out = (float*)d_out;

    const int E = in_sizes[2];
    const int V = in_sizes[0] / DHID;

    // workspace: cursor[V] ints, then perm[E] ints  (~6.6 MB)
    int* cursor = (int*)d_ws;
    int* perm   = cursor + V;

    const int n4 = out_size / 4;
    zero_kernel<<<1024, 256, 0, stream>>>((float4*)out, n4, cursor, V);
    hist_kernel<<<2048, 256, 0, stream>>>(dstI, E, cursor);
    scan_kernel<<<1, 1024, 0, stream>>>(cursor, V);
    scatter_kernel<<<2048, 256, 0, stream>>>(dstI, E, cursor, perm);

    const int ntiles = (E + TE - 1) / TE;
    const int grid = ntiles < 512 ? ntiles : 512;
    cfconv_sorted<<<grid, THREADS, 0, stream>>>(node_feats, coords, srcI, dstI,
                                                W1, W2, perm, out, E, ntiles);
}

// Round 6
// 841.237 us; speedup vs baseline: 3.3701x; 1.6427x over previous
//
#include <hip/hip_runtime.h>

// ContinuousFilterConvolution (SchNet CFConv), MI355X gfx950.
// V=50000, E=1600000, DH=128, NB=16. fp32 in/out.
// Round 6: W2 GEMM moved to fp16 MFMA (v_mfma_f32_16x16x32_f16, fp32 accum).
// Rationale: round-5 counters (VALUBusy 58%, occupancy 47%, dur flat) =>
// fp32 VALU GEMM + its LDS feeds are co-limiting (CU-shared LDS pipe).
// MFMA cuts GEMM VALU issue ~6x and GEMM LDS bytes ~8x. fp16 (not bf16):
// 10-bit mantissa keeps absmax in the current 0.03 envelope; values are O(1).

#define DHID 128
#define NBASE 16

constexpr int TE = 128;        // edges per tile
constexpr int THREADS = 1024;  // 16 waves

using f16x8 = __fp16 __attribute__((ext_vector_type(8)));
using f32x4 = float __attribute__((ext_vector_type(4)));

// ---------------- sort-by-dest machinery (rebuilt every launch) ----------------

__global__ void zero_kernel(float4* __restrict__ out4, int n4,
                            int* __restrict__ cursor, int V) {
    for (int i = blockIdx.x * blockDim.x + threadIdx.x; i < n4;
         i += gridDim.x * blockDim.x)
        out4[i] = make_float4(0.f, 0.f, 0.f, 0.f);
    for (int i = blockIdx.x * blockDim.x + threadIdx.x; i < V;
         i += gridDim.x * blockDim.x)
        cursor[i] = 0;
}

__global__ void hist_kernel(const int* __restrict__ dstI, int E,
                            int* __restrict__ cursor) {
    for (int i = blockIdx.x * blockDim.x + threadIdx.x; i < E;
         i += gridDim.x * blockDim.x)
        atomicAdd(&cursor[dstI[i]], 1);
}

// single-block exclusive scan, wave-shuffle based
__global__ __launch_bounds__(1024)
void scan_kernel(int* __restrict__ cursor, int V) {
    __shared__ int sTot[16];
    const int tid = threadIdx.x;
    const int lane = tid & 63;
    const int wid = tid >> 6;
    int carry = 0;
    for (int base = 0; base < V; base += 1024) {
        const int i = base + tid;
        const int orig = (i < V) ? cursor[i] : 0;
        int val = orig;
#pragma unroll
        for (int off = 1; off < 64; off <<= 1) {
            const int n = __shfl_up(val, off, 64);
            if (lane >= off) val += n;
        }
        if (lane == 63) sTot[wid] = val;
        __syncthreads();
        if (wid == 0 && lane < 16) {
            int t = sTot[lane];
#pragma unroll
            for (int off = 1; off < 16; off <<= 1) {
                const int n = __shfl_up(t, off, 16);
                if (lane >= off) t += n;
            }
            sTot[lane] = t;
        }
        __syncthreads();
        const int waveoff = wid ? sTot[wid - 1] : 0;
        if (i < V) cursor[i] = carry + waveoff + val - orig;
        const int ctot = sTot[15];
        __syncthreads();
        carry += ctot;
    }
}

__global__ void scatter_kernel(const int* __restrict__ dstI, int E,
                               int* __restrict__ cursor, int* __restrict__ perm) {
    for (int i = blockIdx.x * blockDim.x + threadIdx.x; i < E;
         i += gridDim.x * blockDim.x) {
        const int pos = atomicAdd(&cursor[dstI[i]], 1);
        perm[pos] = i;
    }
}

// ---------------- fused CFConv, fp16-MFMA GEMM, dest-sorted ----------------

__global__ __launch_bounds__(THREADS, 4)
void cfconv_mfma(const float* __restrict__ node_feats,
                 const float* __restrict__ coords,
                 const int* __restrict__ srcI,
                 const int* __restrict__ dstI,
                 const float* __restrict__ W1,
                 const float* __restrict__ W2,
                 const int* __restrict__ perm,
                 float* __restrict__ out,
                 int E, int ntiles)
{
    // XOR-swizzle on 16B granules: byte_off ^= (row&7)<<4  (T2; G4)
    __shared__ __align__(16) unsigned short sM1h[TE * DHID];   // f16 m1 [e][k], 32 KB
    __shared__ __align__(16) unsigned short sW2t[DHID * DHID]; // f16 W2^T [c][k], 32 KB
    __shared__ float sMsg[TE * DHID];                          // f32 [e][c], 64 KB
    __shared__ int sSrc[TE];
    __shared__ int sDst[TE];

    const int tid = threadIdx.x;
    const int lane = tid & 63;
    const int w = tid >> 6;      // wave 0..15

    // ---- stage W2^T as f16, swizzled (once per block; first use after (B))
    {
        const int c = tid & 127;
        const int kq = (tid >> 7) * 16;      // 16 consecutive k per thread
        f16x8 lo, hi;
#pragma unroll
        for (int i = 0; i < 8; ++i) {
            lo[i] = (__fp16)W2[(kq + i) * DHID + c];
            hi[i] = (__fp16)W2[(kq + 8 + i) * DHID + c];
        }
        char* base = (char*)sW2t + c * 256;
        const int sw = (c & 7) << 4;
        *(f16x8*)(base + ((kq * 2) ^ sw)) = lo;
        *(f16x8*)(base + ((kq * 2 + 16) ^ sw)) = hi;
    }

    // phase-1 mapping
    const int e1 = tid & 127;    // edge within tile
    const int kg = tid >> 7;     // k-group (16 k), wave-uniform
    // GEMM mapping: wave -> 32x32 output quadrant (2x2 MFMA 16x16 tiles)
    const int er = (w >> 2) * 32;    // edge base
    const int cb = (w & 3) * 32;     // channel base
    const int l15 = lane & 15;
    const int lg = lane >> 4;        // 0..3

    constexpr float WIDTH = 4.5f / 15.0f;
    constexpr float COEFF = -0.5f / (WIDTH * WIDTH);

    for (int tile = blockIdx.x; tile < ntiles; tile += gridDim.x) {
        const int ebase = tile * TE;
        __syncthreads();  // (A) prev flush done reading sMsg/sDst; prev GEMM done

        // ---- phase 1: m1[e][k] = relu(rbf(d_e) @ W1), f16 -> sM1h (swizzled)
        {
            int ge = ebase + e1;
            if (ge >= E) ge = E - 1;  // never triggers (E % TE == 0)
            const int pe = perm[ge];
            const int s = srcI[pe];
            const int dv = dstI[pe];
            if (kg == 0) { sSrc[e1] = s; sDst[e1] = dv; }
            const float dx = coords[s * 3 + 0] - coords[dv * 3 + 0];
            const float dy = coords[s * 3 + 1] - coords[dv * 3 + 1];
            const float dz = coords[s * 3 + 2] - coords[dv * 3 + 2];
            const float d = sqrtf(fmaf(dx, dx, fmaf(dy, dy, dz * dz)));
            float rbf[NBASE];
#pragma unroll
            for (int b = 0; b < NBASE; ++b) {
                const float t = d - WIDTH * (float)b;
                rbf[b] = __expf(COEFF * t * t);
            }
            f16x8 lo, hi;
#pragma unroll
            for (int kk = 0; kk < 16; ++kk) {
                const int k = __builtin_amdgcn_readfirstlane(kg * 16 + kk);
                float a = 0.f;
#pragma unroll
                for (int b = 0; b < NBASE; ++b)
                    a = fmaf(rbf[b], W1[b * DHID + k], a);  // SGPR W1 loads
                const __fp16 hv = (__fp16)fmaxf(a, 0.f);
                if (kk < 8) lo[kk] = hv; else hi[kk - 8] = hv;
            }
            char* base = (char*)sM1h + e1 * 256;
            const int sw = (e1 & 7) << 4;
            *(f16x8*)(base + ((kg * 32) ^ sw)) = lo;
            *(f16x8*)(base + ((kg * 32 + 16) ^ sw)) = hi;
        }
        __syncthreads();  // (B)

        // ---- phase 2: MFMA GEMM. m2 = m1(128xK128) @ W2(K128x128)
        // A-frag: lane holds A[row=l15][k=lg*8+j]; B-frag: B[k=lg*8+j][col=l15]
        f32x4 acc00 = {0.f, 0.f, 0.f, 0.f};
        f32x4 acc01 = {0.f, 0.f, 0.f, 0.f};
        f32x4 acc10 = {0.f, 0.f, 0.f, 0.f};
        f32x4 acc11 = {0.f, 0.f, 0.f, 0.f};
        {
            const int ra0 = er + l15, ra1 = er + 16 + l15;
            const int rb0 = cb + l15, rb1 = cb + 16 + l15;
            const char* pa0 = (const char*)sM1h + ra0 * 256;
            const char* pa1 = (const char*)sM1h + ra1 * 256;
            const char* pb0 = (const char*)sW2t + rb0 * 256;
            const char* pb1 = (const char*)sW2t + rb1 * 256;
            const int sa0 = (ra0 & 7) << 4, sa1 = (ra1 & 7) << 4;
            const int sb0 = (rb0 & 7) << 4, sb1 = (rb1 & 7) << 4;
#pragma unroll
            for (int kb = 0; kb < 4; ++kb) {
                const int kbyte = kb * 64 + lg * 16;
                const f16x8 a0 = *(const f16x8*)(pa0 + (kbyte ^ sa0));
                const f16x8 a1 = *(const f16x8*)(pa1 + (kbyte ^ sa1));
                const f16x8 b0 = *(const f16x8*)(pb0 + (kbyte ^ sb0));
                const f16x8 b1 = *(const f16x8*)(pb1 + (kbyte ^ sb1));
                acc00 = __builtin_amdgcn_mfma_f32_16x16x32_f16(a0, b0, acc00, 0, 0, 0);
                acc01 = __builtin_amdgcn_mfma_f32_16x16x32_f16(a0, b1, acc01, 0, 0, 0);
                acc10 = __builtin_amdgcn_mfma_f32_16x16x32_f16(a1, b0, acc10, 0, 0, 0);
                acc11 = __builtin_amdgcn_mfma_f32_16x16x32_f16(a1, b1, acc11, 0, 0, 0);
            }
        }

        // ---- epilogue a: msg = relu(m2) * node_feats[src] -> sMsg[e][c]
        // C/D layout: lane holds (row = lg*4+r, col = l15) of each 16x16 tile.
        // (writes sMsg only; GEMM read sM1h/sW2t -> no barrier needed between)
        {
            const int c0 = cb + l15;        // tj=0 channel
            const int c1 = cb + 16 + l15;   // tj=1 channel
#pragma unroll
            for (int ti = 0; ti < 2; ++ti) {
                const f32x4 d0 = ti ? acc10 : acc00;   // col-block tj=0
                const f32x4 d1 = ti ? acc11 : acc01;   // col-block tj=1
#pragma unroll
                for (int r = 0; r < 4; ++r) {
                    const int e = er + ti * 16 + lg * 4 + r;
                    const int s = sSrc[e];
                    const float nf0 = node_feats[(size_t)s * DHID + c0];
                    const float nf1 = node_feats[(size_t)s * DHID + c1];
                    sMsg[e * DHID + c0] = fmaxf(d0[r], 0.f) * nf0;
                    sMsg[e * DHID + c1] = fmaxf(d1[r], 0.f) * nf1;
                }
            }
        }
        __syncthreads();  // (E)

        // ---- epilogue b: segmented flush (dest-sorted -> compress runs).
        // 256 threads: 32 channel-quads x 8 scanners of 16 edges each.
        if (tid < 256) {
            const int c4 = tid & 31;
            const int sc = tid >> 5;
            int dvs[16];
#pragma unroll
            for (int j = 0; j < 16; ++j) dvs[j] = sDst[sc * 16 + j];
            float4 racc = make_float4(0.f, 0.f, 0.f, 0.f);
            int prev = dvs[0];
#pragma unroll 4
            for (int j = 0; j < 16; ++j) {
                const int e = sc * 16 + j;
                const float4 m = *(const float4*)&sMsg[e * DHID + c4 * 4];
                if (dvs[j] != prev) {
                    float* op = &out[(size_t)prev * DHID + c4 * 4];
                    atomicAdd(op + 0, racc.x);
                    atomicAdd(op + 1, racc.y);
                    atomicAdd(op + 2, racc.z);
                    atomicAdd(op + 3, racc.w);
                    racc = make_float4(0.f, 0.f, 0.f, 0.f);
                    prev = dvs[j];
                }
                racc.x += m.x; racc.y += m.y; racc.z += m.z; racc.w += m.w;
            }
            float* op = &out[(size_t)prev * DHID + c4 * 4];
            atomicAdd(op + 0, racc.x);
            atomicAdd(op + 1, racc.y);
            atomicAdd(op + 2, racc.z);
            atomicAdd(op + 3, racc.w);
        }
    }
}

extern "C" void kernel_launch(void* const* d_in, const int* in_sizes, int n_in,
                              void* d_out, int out_size, void* d_ws, size_t ws_size,
                              hipStream_t stream) {
    const float* node_feats = (const float*)d_in[0];
    const float* coords     = (const float*)d_in[1];
    const int*   srcI       = (const int*)d_in[2];
    const int*   dstI       = (const int*)d_in[3];
    const float* W1         = (const float*)d_in[4];
    const float* W2         = (const float*)d_in[5];
    float* out = (float*)d_out;

    const int E = in_sizes[2];
    const int V = in_sizes[0] / DHID;

    // workspace: cursor[V] ints, then perm[E] ints (~6.6 MB)
    int* cursor = (int*)d_ws;
    int* perm   = cursor + V;

    const int n4 = out_size / 4;
    zero_kernel<<<1024, 256, 0, stream>>>((float4*)out, n4, cursor, V);
    hist_kernel<<<2048, 256, 0, stream>>>(dstI, E, cursor);
    scan_kernel<<<1, 1024, 0, stream>>>(cursor, V);
    scatter_kernel<<<2048, 256, 0, stream>>>(dstI, E, cursor, perm);

    const int ntiles = (E + TE - 1) / TE;
    const int grid = ntiles < 512 ? ntiles : 512;
    cfconv_mfma<<<grid, THREADS, 0, stream>>>(node_feats, coords, srcI, dstI,
                                              W1, W2, perm, out, E, ntiles);
}

// Round 7
// 699.718 us; speedup vs baseline: 4.0518x; 1.2023x over previous
//
#include <hip/hip_runtime.h>

// ContinuousFilterConvolution (SchNet CFConv), MI355X gfx950.
// V=50000, E=1600000, DH=128, NB=16. fp32 in/out.
// Round 7: (a) swapped-operand MFMA (D = W2^T·m1^T) so each lane holds 4
// channels of ONE edge -> in-register segmented flush via shfl_up(.,off,16)
// scan; sMsg + barrier(E) + serial tid<256 flush deleted. LDS 129->65 KB =>
// 2 blocks/CU (launch_bounds(1024,8), VGPR<=64). (b) single-block scan ->
// 3-kernel parallel scan (round-6 prep was ~285us, mostly the 1-CU scan).

#define DHID 128
#define NBASE 16

constexpr int TE = 128;        // edges per tile
constexpr int THREADS = 1024;  // 16 waves

using f16x8 = __fp16 __attribute__((ext_vector_type(8)));
using f32x4 = float __attribute__((ext_vector_type(4)));

// ---------------- sort-by-dest machinery (rebuilt every launch) ----------------

__global__ void zero_kernel(float4* __restrict__ out4, int n4,
                            int* __restrict__ cursor, int V) {
    for (int i = blockIdx.x * blockDim.x + threadIdx.x; i < n4;
         i += gridDim.x * blockDim.x)
        out4[i] = make_float4(0.f, 0.f, 0.f, 0.f);
    for (int i = blockIdx.x * blockDim.x + threadIdx.x; i < V;
         i += gridDim.x * blockDim.x)
        cursor[i] = 0;
}

__global__ void hist_kernel(const int* __restrict__ dstI, int E,
                            int* __restrict__ cursor) {
    for (int i = blockIdx.x * blockDim.x + threadIdx.x; i < E;
         i += gridDim.x * blockDim.x)
        atomicAdd(&cursor[dstI[i]], 1);
}

constexpr int SCAN_BS = 256;  // one element per thread per chunk

__global__ __launch_bounds__(SCAN_BS)
void scan_partial(const int* __restrict__ cursor, int V, int* __restrict__ sums) {
    const int i = blockIdx.x * SCAN_BS + threadIdx.x;
    int v = (i < V) ? cursor[i] : 0;
#pragma unroll
    for (int off = 32; off; off >>= 1) v += __shfl_down(v, off, 64);
    __shared__ int ws[4];
    if ((threadIdx.x & 63) == 0) ws[threadIdx.x >> 6] = v;
    __syncthreads();
    if (threadIdx.x == 0) sums[blockIdx.x] = ws[0] + ws[1] + ws[2] + ws[3];
}

__global__ __launch_bounds__(SCAN_BS)
void scan_sums(int* __restrict__ sums, int nch) {   // nch <= 256
    const int tid = threadIdx.x;
    const int lane = tid & 63, w = tid >> 6;
    const int v = (tid < nch) ? sums[tid] : 0;
    int s = v;
#pragma unroll
    for (int off = 1; off < 64; off <<= 1) {
        const int n = __shfl_up(s, off, 64);
        if (lane >= off) s += n;
    }
    __shared__ int wt[4];
    if (lane == 63) wt[w] = s;
    __syncthreads();
    int off = 0;
    for (int j = 0; j < w; ++j) off += wt[j];
    if (tid < nch) sums[tid] = off + s - v;  // exclusive
}

__global__ __launch_bounds__(SCAN_BS)
void scan_apply(int* __restrict__ cursor, int V, const int* __restrict__ sums) {
    const int i = blockIdx.x * SCAN_BS + threadIdx.x;
    const int lane = threadIdx.x & 63, w = threadIdx.x >> 6;
    const int v = (i < V) ? cursor[i] : 0;
    int s = v;
#pragma unroll
    for (int off = 1; off < 64; off <<= 1) {
        const int n = __shfl_up(s, off, 64);
        if (lane >= off) s += n;
    }
    __shared__ int wt[4];
    if (lane == 63) wt[w] = s;
    __syncthreads();
    int off = sums[blockIdx.x];
    for (int j = 0; j < w; ++j) off += wt[j];
    if (i < V) cursor[i] = off + s - v;  // exclusive prefix = bucket start
}

__global__ void scatter_kernel(const int* __restrict__ dstI, int E,
                               int* __restrict__ cursor, int* __restrict__ perm) {
    for (int i = blockIdx.x * blockDim.x + threadIdx.x; i < E;
         i += gridDim.x * blockDim.x) {
        const int pos = atomicAdd(&cursor[dstI[i]], 1);
        perm[pos] = i;
    }
}

// ---------------- fused CFConv, fp16-MFMA, in-register segmented flush ----------------

__global__ __launch_bounds__(THREADS, 8)
void cfconv_mfma(const float* __restrict__ node_feats,
                 const float* __restrict__ coords,
                 const int* __restrict__ srcI,
                 const int* __restrict__ dstI,
                 const float* __restrict__ W1,
                 const float* __restrict__ W2,
                 const int* __restrict__ perm,
                 float* __restrict__ out,
                 int E, int ntiles)
{
    // XOR-swizzle on 16B granules: byte_off ^= (row&7)<<4  (T2; G4)
    __shared__ __align__(16) unsigned short sM1h[TE * DHID];   // f16 m1 [e][k], 32 KB
    __shared__ __align__(16) unsigned short sW2t[DHID * DHID]; // f16 W2^T [c][k], 32 KB
    __shared__ int sSrc[TE];
    __shared__ int sDst[TE];

    const int tid = threadIdx.x;
    const int lane = tid & 63;
    const int w = tid >> 6;      // wave 0..15

    // ---- stage W2^T as f16, swizzled (once per block)
    {
        const int c = tid & 127;
        const int kq = (tid >> 7) * 16;      // 16 consecutive k per thread
        f16x8 lo, hi;
#pragma unroll
        for (int i = 0; i < 8; ++i) {
            lo[i] = (__fp16)W2[(kq + i) * DHID + c];
            hi[i] = (__fp16)W2[(kq + 8 + i) * DHID + c];
        }
        char* base = (char*)sW2t + c * 256;
        const int sw = (c & 7) << 4;
        *(f16x8*)(base + ((kq * 2) ^ sw)) = lo;
        *(f16x8*)(base + ((kq * 2 + 16) ^ sw)) = hi;
    }

    // phase-1 mapping
    const int e1 = tid & 127;    // edge within tile
    const int kg = tid >> 7;     // k-group (16 k), wave-uniform
    // GEMM mapping: wave -> 32 edges x 32 channels quadrant
    const int er = (w >> 2) * 32;    // edge base
    const int cb = (w & 3) * 32;     // channel base
    const int l15 = lane & 15;
    const int lg = lane >> 4;        // 0..3

    constexpr float WIDTH = 4.5f / 15.0f;
    constexpr float COEFF = -0.5f / (WIDTH * WIDTH);

    for (int tile = blockIdx.x; tile < ntiles; tile += gridDim.x) {
        const int ebase = tile * TE;
        __syncthreads();  // (A) prev tile fully consumed (sM1h/sSrc/sDst)

        // ---- phase 1: m1[e][k] = relu(rbf(d_e) @ W1), f16 -> sM1h (swizzled)
        {
            int ge = ebase + e1;
            if (ge >= E) ge = E - 1;  // never triggers (E % TE == 0)
            const int pe = perm[ge];
            const int s = srcI[pe];
            const int dv = dstI[pe];
            if (kg == 0) { sSrc[e1] = s; sDst[e1] = dv; }
            const float dx = coords[s * 3 + 0] - coords[dv * 3 + 0];
            const float dy = coords[s * 3 + 1] - coords[dv * 3 + 1];
            const float dz = coords[s * 3 + 2] - coords[dv * 3 + 2];
            const float d = sqrtf(fmaf(dx, dx, fmaf(dy, dy, dz * dz)));
            float rbf[NBASE];
#pragma unroll
            for (int b = 0; b < NBASE; ++b) {
                const float t = d - WIDTH * (float)b;
                rbf[b] = __expf(COEFF * t * t);
            }
            f16x8 lo, hi;
#pragma unroll
            for (int kk = 0; kk < 16; ++kk) {
                const int k = __builtin_amdgcn_readfirstlane(kg * 16 + kk);
                float a = 0.f;
#pragma unroll
                for (int b = 0; b < NBASE; ++b)
                    a = fmaf(rbf[b], W1[b * DHID + k], a);  // SGPR W1 loads
                const __fp16 hv = (__fp16)fmaxf(a, 0.f);
                if (kk < 8) lo[kk] = hv; else hi[kk - 8] = hv;
            }
            char* base = (char*)sM1h + e1 * 256;
            const int sw = (e1 & 7) << 4;
            *(f16x8*)(base + ((kg * 32) ^ sw)) = lo;
            *(f16x8*)(base + ((kg * 32 + 16) ^ sw)) = hi;
        }
        __syncthreads();  // (B)

        // ---- phase 2: swapped MFMA. q = W2^T(c x k) · m1^T(k x e)
        // C/D: col=lane&15 = EDGE, row=lg*4+reg = CHANNEL  -> lane owns 4
        // channels of one edge; dest runs lie along 16-lane groups.
        f32x4 q00 = {0.f,0.f,0.f,0.f};  // tj=0 channels, ti=0 edges
        f32x4 q01 = {0.f,0.f,0.f,0.f};  // tj=0, ti=1
        f32x4 q10 = {0.f,0.f,0.f,0.f};  // tj=1, ti=0
        f32x4 q11 = {0.f,0.f,0.f,0.f};  // tj=1, ti=1
        {
            const int ra0 = er + l15, ra1 = er + 16 + l15;       // edge rows
            const int rb0 = cb + l15, rb1 = cb + 16 + l15;       // channel rows
            const char* pa0 = (const char*)sM1h + ra0 * 256;
            const char* pa1 = (const char*)sM1h + ra1 * 256;
            const char* pb0 = (const char*)sW2t + rb0 * 256;
            const char* pb1 = (const char*)sW2t + rb1 * 256;
            const int sa0 = (ra0 & 7) << 4, sa1 = (ra1 & 7) << 4;
            const int sb0 = (rb0 & 7) << 4, sb1 = (rb1 & 7) << 4;
#pragma unroll
            for (int kb = 0; kb < 4; ++kb) {
                const int kbyte = kb * 64 + lg * 16;
                const f16x8 a0 = *(const f16x8*)(pa0 + (kbyte ^ sa0));
                const f16x8 a1 = *(const f16x8*)(pa1 + (kbyte ^ sa1));
                const f16x8 b0 = *(const f16x8*)(pb0 + (kbyte ^ sb0));
                const f16x8 b1 = *(const f16x8*)(pb1 + (kbyte ^ sb1));
                q00 = __builtin_amdgcn_mfma_f32_16x16x32_f16(b0, a0, q00, 0, 0, 0);
                q01 = __builtin_amdgcn_mfma_f32_16x16x32_f16(b0, a1, q01, 0, 0, 0);
                q10 = __builtin_amdgcn_mfma_f32_16x16x32_f16(b1, a0, q10, 0, 0, 0);
                q11 = __builtin_amdgcn_mfma_f32_16x16x32_f16(b1, a1, q11, 0, 0, 0);
            }
        }

        // ---- epilogue: relu * node_feats gather, then in-register segmented
        // flush (dests sorted => contiguous runs along l15).
#pragma unroll
        for (int ti = 0; ti < 2; ++ti) {
            const int e = er + ti * 16 + l15;
            const int dv = sDst[e];
            const int s = sSrc[e];
            bool pr1, pr2, pr4, pr8;
            {
                int nd;
                nd = __shfl_up(dv, 1, 16); pr1 = (l15 >= 1) && (nd == dv);
                nd = __shfl_up(dv, 2, 16); pr2 = (l15 >= 2) && (nd == dv);
                nd = __shfl_up(dv, 4, 16); pr4 = (l15 >= 4) && (nd == dv);
                nd = __shfl_up(dv, 8, 16); pr8 = (l15 >= 8) && (nd == dv);
            }
            const int ndn = __shfl_down(dv, 1, 16);
            const bool tail = (l15 == 15) || (ndn != dv);
#pragma unroll
            for (int tj = 0; tj < 2; ++tj) {
                const f32x4 q = tj ? (ti ? q11 : q10) : (ti ? q01 : q00);
                const int c0 = cb + tj * 16 + lg * 4;
                const float4 nf = *(const float4*)&node_feats[(size_t)s * DHID + c0];
                float m0 = fmaxf(q[0], 0.f) * nf.x;
                float m1 = fmaxf(q[1], 0.f) * nf.y;
                float m2 = fmaxf(q[2], 0.f) * nf.z;
                float m3 = fmaxf(q[3], 0.f) * nf.w;
                float t0, t1, t2, t3;
                t0 = __shfl_up(m0, 1, 16); t1 = __shfl_up(m1, 1, 16);
                t2 = __shfl_up(m2, 1, 16); t3 = __shfl_up(m3, 1, 16);
                if (pr1) { m0 += t0; m1 += t1; m2 += t2; m3 += t3; }
                t0 = __shfl_up(m0, 2, 16); t1 = __shfl_up(m1, 2, 16);
                t2 = __shfl_up(m2, 2, 16); t3 = __shfl_up(m3, 2, 16);
                if (pr2) { m0 += t0; m1 += t1; m2 += t2; m3 += t3; }
                t0 = __shfl_up(m0, 4, 16); t1 = __shfl_up(m1, 4, 16);
                t2 = __shfl_up(m2, 4, 16); t3 = __shfl_up(m3, 4, 16);
                if (pr4) { m0 += t0; m1 += t1; m2 += t2; m3 += t3; }
                t0 = __shfl_up(m0, 8, 16); t1 = __shfl_up(m1, 8, 16);
                t2 = __shfl_up(m2, 8, 16); t3 = __shfl_up(m3, 8, 16);
                if (pr8) { m0 += t0; m1 += t1; m2 += t2; m3 += t3; }
                if (tail) {   // inclusive sum at tail = full run sum
                    float* op = &out[(size_t)dv * DHID + c0];
                    atomicAdd(op + 0, m0);
                    atomicAdd(op + 1, m1);
                    atomicAdd(op + 2, m2);
                    atomicAdd(op + 3, m3);
                }
            }
        }
    }
}

extern "C" void kernel_launch(void* const* d_in, const int* in_sizes, int n_in,
                              void* d_out, int out_size, void* d_ws, size_t ws_size,
                              hipStream_t stream) {
    const float* node_feats = (const float*)d_in[0];
    const float* coords     = (const float*)d_in[1];
    const int*   srcI       = (const int*)d_in[2];
    const int*   dstI       = (const int*)d_in[3];
    const float* W1         = (const float*)d_in[4];
    const float* W2         = (const float*)d_in[5];
    float* out = (float*)d_out;

    const int E = in_sizes[2];
    const int V = in_sizes[0] / DHID;

    // workspace: cursor[V], perm[E], sums[nch]  (~6.6 MB)
    int* cursor = (int*)d_ws;
    int* perm   = cursor + V;
    const int nch = (V + SCAN_BS - 1) / SCAN_BS;   // 196 <= 256
    int* sums   = perm + E;

    const int n4 = out_size / 4;
    zero_kernel<<<1024, 256, 0, stream>>>((float4*)out, n4, cursor, V);
    hist_kernel<<<2048, 256, 0, stream>>>(dstI, E, cursor);
    scan_partial<<<nch, SCAN_BS, 0, stream>>>(cursor, V, sums);
    scan_sums<<<1, SCAN_BS, 0, stream>>>(sums, nch);
    scan_apply<<<nch, SCAN_BS, 0, stream>>>(cursor, V, sums);
    scatter_kernel<<<2048, 256, 0, stream>>>(dstI, E, cursor, perm);

    const int ntiles = (E + TE - 1) / TE;
    const int grid = ntiles < 512 ? ntiles : 512;
    cfconv_mfma<<<grid, THREADS, 0, stream>>>(node_feats, coords, srcI, dstI,
                                              W1, W2, perm, out, E, ntiles);
}